// Round 9
// baseline (1838.922 us; speedup 1.0000x reference)
//
#include <hip/hip_runtime.h>
#include <cstdint>
#include <cstddef>

// Problem constants
#define LSEQ 2048
#define BB   32
#define DD   1024
#define NLAYERS 4
#define MM   (LSEQ*BB)      // 65536 rows
#define BD   (BB*DD)        // 32768
#define CHUNK 32
#define NCHUNK (LSEQ/CHUNK) // 64

typedef _Float16 f16;
typedef __attribute__((ext_vector_type(8))) _Float16 f16x8;
typedef __attribute__((ext_vector_type(4))) float f32x4;

// ---------------- scan: h[t] = a*h[t-1] + x[t], a = exp(A_log[d]) ----------------

__global__ void scan_pass1(const float* __restrict__ x, const float* __restrict__ Alog,
                           f16* __restrict__ h, float* __restrict__ carry) {
    int tid = blockIdx.x * blockDim.x + threadIdx.x;   // 2M threads
    int bd  = tid & (BD - 1);
    int c   = tid >> 15;                               // chunk id
    float a = expf(Alog[bd & (DD - 1)]);
    size_t base = (size_t)c * CHUNK * BD + bd;
    float hv = 0.f;
#pragma unroll
    for (int i = 0; i < CHUNK; ++i) {
        hv = a * hv + x[base + (size_t)i * BD];
        h[base + (size_t)i * BD] = (f16)hv;
    }
    carry[c * BD + bd] = hv;
}

__global__ void scan_pass2(const float* __restrict__ Alog, float* __restrict__ carry) {
    int bd = blockIdx.x * blockDim.x + threadIdx.x;    // 32768 threads
    float d32 = expf((float)CHUNK * Alog[bd & (DD - 1)]);  // a^CHUNK
    float cin = 0.f;
    for (int c = 0; c < NCHUNK; ++c) {
        float co = carry[c * BD + bd];
        carry[c * BD + bd] = cin;       // exclusive carry-in
        cin = d32 * cin + co;
    }
}

__global__ void scan_pass3(const float* __restrict__ Alog, const float* __restrict__ carry,
                           f16* __restrict__ h) {
    int tid = blockIdx.x * blockDim.x + threadIdx.x;
    int bd  = tid & (BD - 1);
    int c   = tid >> 15;
    float a   = expf(Alog[bd & (DD - 1)]);
    float cin = carry[c * BD + bd];
    size_t base = (size_t)c * CHUNK * BD + bd;
    float p = a;
#pragma unroll
    for (int i = 0; i < CHUNK; ++i) {
        size_t idx = base + (size_t)i * BD;
        float hv = (float)h[idx] + p * cin;
        h[idx] = (f16)hv;
        p *= a;
    }
}

// ---------------- fp32 -> fp16 weight conversion ----------------

__global__ void cvt_w(const float* __restrict__ w, f16* __restrict__ o, int n) {
    int i = (blockIdx.x * blockDim.x + threadIdx.x) * 4;
    if (i + 3 < n) {
        float4 v = *(const float4*)&w[i];
        o[i + 0] = (f16)v.x; o[i + 1] = (f16)v.y;
        o[i + 2] = (f16)v.z; o[i + 3] = (f16)v.w;
    }
}

// ---------------- GEMM + bias + tanh: 1 barrier/K-tile, full cross-tile pipeline ----------------
// C[m][n] = tanh(sum_k A[m][k]*W[n][k] + b[n])
// Tile 256x256, BK=64, 16 K-tiles, 2 LDS buffers alternating even/odd (128 KiB).
// 512 thr = 8 waves (2Mx4N), wave tile 128x64, mfma 16x16x32 f16, acc 8x4.
// Phase t (cur=t&1, oth=cur^1); invariant: k0 frags of tile t already in regs:
//   read12(cur,k1) -> a1,b1        [drain under k0 cluster]
//   MFMA32(a0,b0)                  [k0 of tile t]
//   s_waitcnt vmcnt(0) lgkmcnt(0)  [cur fully read by this wave; tile t+1 landed]
//   s_barrier                      [block-wide: publishes oth(t+1), frees cur]
//   stage(t+2 -> cur)              [8 gloads; ~1.5 phases to land before drain]
//   read12(oth, k0 of t+1) -> a0,b0  [drain under k1 cluster]
//   MFMA32(a1,b1)                  [k1 of tile t]
// Every read burst + stage issue drains under an MFMA cluster. The vmcnt(0)
// is cheap: queue holds only tile t+1's 8 loads issued one phase earlier.
// T2: chunk ^= (row&7) swizzle, inverse-swz global src, linear gload_lds dest.
// T5: setprio around MFMA clusters. T1: XCD-chunked block swizzle.

#define BM 256
#define BN 256
#define BK 64
#define KK 1024
#define NN 1024
#define NKTILE (KK / BK)     // 16

__device__ __forceinline__ void gload_lds16(const void* g, void* l) {
    __builtin_amdgcn_global_load_lds((const __attribute__((address_space(1))) unsigned int*)g,
                                     (__attribute__((address_space(3))) unsigned int*)l,
                                     16, 0, 0);
}

// stage one half-tile: 128 rows x 64 f16 = 16 KiB, 2 loads/thread.
__device__ __forceinline__ void stage_half(const f16* __restrict__ gbase, f16* region, int tid) {
#pragma unroll
    for (int j = 0; j < 2; ++j) {
        int s = tid + j * 512;               // 16B slot 0..1023
        int r = s >> 3;                      // local row 0..127
        int c = (s & 7) ^ (r & 7);           // inverse-swizzled source chunk
        gload_lds16(gbase + (size_t)r * KK + c * 8, region + (size_t)s * 8);
    }
}

// stage a full 256x64 K-tile (A and W): 8 loads/thread
__device__ __forceinline__ void stage_tile(const f16* __restrict__ gA, const f16* __restrict__ gW,
                                           f16* As, f16* Bs, int tid) {
    stage_half(gA,                    As,        tid);
    stage_half(gA + (size_t)128 * KK, As + 8192, tid);
    stage_half(gW,                    Bs,        tid);
    stage_half(gW + (size_t)128 * KK, Bs + 8192, tid);
}

// swizzled fragment read from a [256][64] f16 tile
__device__ __forceinline__ f16x8 rd(const f16* base, int row, int chunk) {
    int c = chunk ^ (row & 7);
    return *(const f16x8*)(base + row * 64 + c * 8);
}

__device__ __forceinline__ void read12(const f16* Abase, const f16* Bbase,
                                       int arow, int brow, int kc,
                                       f16x8 a[8], f16x8 b[4]) {
#pragma unroll
    for (int m = 0; m < 8; ++m) a[m] = rd(Abase, arow + m * 16, kc);
#pragma unroll
    for (int n = 0; n < 4; ++n) b[n] = rd(Bbase, brow + n * 16, kc);
}

__device__ __forceinline__ float tanh_fast(float z) {
    float e = __expf(2.f * z);
    return 1.f - 2.f / (e + 1.f);
}

#define BAR() do { __builtin_amdgcn_sched_barrier(0); __builtin_amdgcn_s_barrier(); \
                   __builtin_amdgcn_sched_barrier(0); } while (0)

#define MFMA32(av, bv) do {                                                     \
    __builtin_amdgcn_s_setprio(1);                                              \
    _Pragma("unroll")                                                           \
    for (int m = 0; m < 8; ++m)                                                 \
        _Pragma("unroll")                                                       \
        for (int n = 0; n < 4; ++n)                                             \
            acc[m][n] = __builtin_amdgcn_mfma_f32_16x16x32_f16(av[m], bv[n],    \
                                                               acc[m][n], 0, 0, 0); \
    __builtin_amdgcn_s_setprio(0);                                              \
} while (0)

__global__ __launch_bounds__(512, 2) void gemm_tanh(const f16* __restrict__ A,
                                                    const f16* __restrict__ W,
                                                    const float* __restrict__ bias,
                                                    f16* __restrict__ C) {
    __shared__ f16 As[2][BM * BK];   // 2 x 32 KiB
    __shared__ f16 Bs[2][BN * BK];   // 2 x 32 KiB

    const int tid  = threadIdx.x;
    const int lane = tid & 63;
    const int wid  = tid >> 6;        // 0..7
    const int wr   = wid >> 2;        // 0..1  (M half)
    const int wc   = wid & 3;         // 0..3  (N quarter)

    // T1: XCD-chunked bijective swizzle (nwg=1024, %8==0)
    const int cpx = gridDim.x >> 3;
    const int lin = ((int)blockIdx.x & 7) * cpx + ((int)blockIdx.x >> 3);
    const int tm  = (lin >> 2) * BM;
    const int tn  = (lin & 3) * BN;

    const f16* Ab = A + (size_t)tm * KK;
    const f16* Wb = W + (size_t)tn * KK;

    const int fr = lane & 15;         // fragment row within 16
    const int fc = lane >> 4;         // 16B k-chunk 0..3 within a 32-k step

    f32x4 acc[8][4];
#pragma unroll
    for (int i = 0; i < 8; ++i)
#pragma unroll
        for (int j = 0; j < 4; ++j)
            acc[i][j] = (f32x4){0.f, 0.f, 0.f, 0.f};

    // prologue: tile0 -> buf0, tile1 -> buf1 (16 loads/thread in flight)
    stage_tile(Ab,      Wb,      &As[0][0], &Bs[0][0], tid);
    stage_tile(Ab + 64, Wb + 64, &As[1][0], &Bs[1][0], tid);
    asm volatile("s_waitcnt vmcnt(8)" ::: "memory");   // tile0 landed
    BAR();

    const int arow = wr * 128 + fr;
    const int brow = wc * 64  + fr;

    f16x8 a0[8], b0[4], a1[8], b1[4];
    read12(&As[0][0], &Bs[0][0], arow, brow, fc, a0, b0);   // k0 of tile0

#pragma unroll 2
    for (int t = 0; t < NKTILE; ++t) {
        const int cur = t & 1, oth = cur ^ 1;

        read12(&As[cur][0], &Bs[cur][0], arow, brow, 4 + fc, a1, b1);  // k1(cur)
        MFMA32(a0, b0);                                     // k0 cluster (pre-read)
        asm volatile("s_waitcnt vmcnt(0) lgkmcnt(0)" ::: "memory");
        // ^ cur fully read by this wave; tile t+1's 8 loads (issued last phase) landed
        BAR();                                              // publish oth(t+1), free cur
        if (t + 2 < NKTILE)
            stage_tile(Ab + (size_t)(t + 2) * BK, Wb + (size_t)(t + 2) * BK,
                       &As[cur][0], &Bs[cur][0], tid);      // t+2 -> cur
        if (t + 1 < NKTILE)
            read12(&As[oth][0], &Bs[oth][0], arow, brow, fc, a0, b0);  // k0(t+1)
        MFMA32(a1, b1);                                     // k1 cluster; reads drain under
    }

    // epilogue: bias + fast tanh, store f16 (mi outer: row-major store order)
#pragma unroll
    for (int mi = 0; mi < 8; ++mi) {
        const int r0 = tm + wr * 128 + mi * 16 + (fc << 2);
#pragma unroll
        for (int ni = 0; ni < 4; ++ni) {
            const int c = tn + wc * 64 + ni * 16 + fr;
            const float bv = bias[c];
#pragma unroll
            for (int q = 0; q < 4; ++q) {
                float z = acc[mi][ni][q] + bv;
                C[(size_t)(r0 + q) * NN + c] = (f16)tanh_fast(z);
            }
        }
    }
}

// ---------------- head: out[m] = sum_d h[m][d]*hw[d] + hb ----------------

__global__ void head_k(const f16* __restrict__ h, const float* __restrict__ hw,
                       const float* __restrict__ hb, float* __restrict__ out) {
    const int row  = blockIdx.x * 4 + (threadIdx.x >> 6);
    const int lane = threadIdx.x & 63;
    const f16* hr = h + (size_t)row * DD;
    float s = 0.f;
#pragma unroll
    for (int j = 0; j < DD / 64; ++j) {
        int d = lane + j * 64;
        s += (float)hr[d] * hw[d];
    }
#pragma unroll
    for (int o = 32; o > 0; o >>= 1) s += __shfl_down(s, o, 64);
    if (lane == 0) out[row] = s + hb[0];
}

// ---------------- launch ----------------

extern "C" void kernel_launch(void* const* d_in, const int* in_sizes, int n_in,
                              void* d_out, int out_size, void* d_ws, size_t ws_size,
                              hipStream_t stream) {
    const float* x    = (const float*)d_in[0];
    const float* Alog = (const float*)d_in[1];
    const float* Wls  = (const float*)d_in[2];
    const float* bls  = (const float*)d_in[3];
    const float* hw   = (const float*)d_in[4];
    const float* hb   = (const float*)d_in[5];
    float* out = (float*)d_out;

    char* ws = (char*)d_ws;
    const size_t hbytes = (size_t)MM * DD * sizeof(f16);   // 128 MiB
    f16* h0 = (f16*)ws;
    f16* h1 = (f16*)(ws + hbytes);
    char* scratch = ws + 2 * hbytes;
    float* carry = (float*)scratch;                         // 8 MiB, scan phase only
    f16*   wf    = (f16*)scratch;                           // 8 MiB, reused after scan

    // 1. scan (chunked, 3 passes)
    scan_pass1<<<(NCHUNK * BD) / 256, 256, 0, stream>>>(x, Alog, h0, carry);
    scan_pass2<<<BD / 256, 256, 0, stream>>>(Alog, carry);
    scan_pass3<<<(NCHUNK * BD) / 256, 256, 0, stream>>>(Alog, carry, h0);

    // 2. weights fp32 -> fp16 (reuses carry region; stream-ordered after pass3)
    cvt_w<<<(NLAYERS * DD * DD / 4) / 256, 256, 0, stream>>>(Wls, wf, NLAYERS * DD * DD);

    // 3. four layers, ping-pong (1-D grid of 1024 blocks, swizzles inside kernel)
    dim3 grid((MM / BM) * (NN / BN)), blk(512);
    gemm_tanh<<<grid, blk, 0, stream>>>(h0, wf + 0 * (DD * DD), bls + 0 * DD, h1);
    gemm_tanh<<<grid, blk, 0, stream>>>(h1, wf + 1 * (DD * DD), bls + 1 * DD, h0);
    gemm_tanh<<<grid, blk, 0, stream>>>(h0, wf + 2 * (DD * DD), bls + 2 * DD, h1);
    gemm_tanh<<<grid, blk, 0, stream>>>(h1, wf + 3 * (DD * DD), bls + 3 * DD, h0);

    // 4. head
    head_k<<<MM / 4, 256, 0, stream>>>(h0, hw, hb, out);
}

// Round 10
// 747.941 us; speedup vs baseline: 2.4586x; 2.4586x over previous
//
#include <hip/hip_runtime.h>
#include <cstdint>
#include <cstddef>

// Problem constants
#define LSEQ 2048
#define BB   32
#define DD   1024
#define NLAYERS 4
#define MM   (LSEQ*BB)      // 65536 rows
#define BD   (BB*DD)        // 32768
#define CHUNK 32
#define NCHUNK (LSEQ/CHUNK) // 64

typedef _Float16 f16;
typedef __attribute__((ext_vector_type(8))) _Float16 f16x8;
typedef __attribute__((ext_vector_type(4))) float f32x4;

// ---------------- scan: h[t] = a*h[t-1] + x[t], a = exp(A_log[d]) ----------------

__global__ void scan_pass1(const float* __restrict__ x, const float* __restrict__ Alog,
                           f16* __restrict__ h, float* __restrict__ carry) {
    int tid = blockIdx.x * blockDim.x + threadIdx.x;   // 2M threads
    int bd  = tid & (BD - 1);
    int c   = tid >> 15;                               // chunk id
    float a = expf(Alog[bd & (DD - 1)]);
    size_t base = (size_t)c * CHUNK * BD + bd;
    float hv = 0.f;
#pragma unroll
    for (int i = 0; i < CHUNK; ++i) {
        hv = a * hv + x[base + (size_t)i * BD];
        h[base + (size_t)i * BD] = (f16)hv;
    }
    carry[c * BD + bd] = hv;
}

__global__ void scan_pass2(const float* __restrict__ Alog, float* __restrict__ carry) {
    int bd = blockIdx.x * blockDim.x + threadIdx.x;    // 32768 threads
    float d32 = expf((float)CHUNK * Alog[bd & (DD - 1)]);  // a^CHUNK
    float cin = 0.f;
    for (int c = 0; c < NCHUNK; ++c) {
        float co = carry[c * BD + bd];
        carry[c * BD + bd] = cin;       // exclusive carry-in
        cin = d32 * cin + co;
    }
}

__global__ void scan_pass3(const float* __restrict__ Alog, const float* __restrict__ carry,
                           f16* __restrict__ h) {
    int tid = blockIdx.x * blockDim.x + threadIdx.x;
    int bd  = tid & (BD - 1);
    int c   = tid >> 15;
    float a   = expf(Alog[bd & (DD - 1)]);
    float cin = carry[c * BD + bd];
    size_t base = (size_t)c * CHUNK * BD + bd;
    float p = a;
#pragma unroll
    for (int i = 0; i < CHUNK; ++i) {
        size_t idx = base + (size_t)i * BD;
        float hv = (float)h[idx] + p * cin;
        h[idx] = (f16)hv;
        p *= a;
    }
}

// ---------------- fp32 -> fp16 weight conversion ----------------

__global__ void cvt_w(const float* __restrict__ w, f16* __restrict__ o, int n) {
    int i = (blockIdx.x * blockDim.x + threadIdx.x) * 4;
    if (i + 3 < n) {
        float4 v = *(const float4*)&w[i];
        o[i + 0] = (f16)v.x; o[i + 1] = (f16)v.y;
        o[i + 2] = (f16)v.z; o[i + 3] = (f16)v.w;
    }
}

// ---------------- GEMM + bias + tanh: R7 schedule (2 barriers/K-tile) ----------------
// C[m][n] = tanh(sum_k A[m][k]*W[n][k] + b[n])
// Tile 256x256, BK=64, 16 K-tiles, LDS buffers alternate even/odd (128 KiB).
// 512 thr = 8 waves (2Mx4N), wave tile 128x64, mfma 16x16x32 f16, acc 8x4.
// Measured-best schedule (R7: 167 us, 822 TF, MfmaUtil 35%, no spill):
//   read24(cur)  [k0 group then k1 group, NO barrier after]
//   MFMA32(k0)   <- compiler emits counted lgkmcnt: k1 reads drain under it
//   lgkm0; BAR1  <- cur fully read block-wide, safe to overwrite
//   stage(t+2 -> cur buf); MFMA32(k1)  <- gload issue overlaps cluster
//   vmcnt(8); BAR2  <- t+1 landed & published (vmcnt(0) only at tail)
// T2: chunk ^= (row&7) swizzle, inverse-swz global src, linear gload_lds dest.
// T5: setprio around MFMA clusters. T1: XCD-chunked block swizzle.
// FUSED-HEAD mode (pbuf != nullptr, layer 4 only): instead of storing C,
// each thread dots its tanh outputs with hw[c], shfl-reduces over the 16
// fr-lanes, accumulates across waves via a 4 KB LDS buffer (reuses As), and
// writes per-(row, N-block) partials; head_final sums 4 partials + bias.

#define BM 256
#define BN 256
#define BK 64
#define KK 1024
#define NN 1024
#define NKTILE (KK / BK)     // 16

__device__ __forceinline__ void gload_lds16(const void* g, void* l) {
    __builtin_amdgcn_global_load_lds((const __attribute__((address_space(1))) unsigned int*)g,
                                     (__attribute__((address_space(3))) unsigned int*)l,
                                     16, 0, 0);
}

// stage one half-tile: 128 rows x 64 f16 = 16 KiB, 2 loads/thread.
__device__ __forceinline__ void stage_half(const f16* __restrict__ gbase, f16* region, int tid) {
#pragma unroll
    for (int j = 0; j < 2; ++j) {
        int s = tid + j * 512;               // 16B slot 0..1023
        int r = s >> 3;                      // local row 0..127
        int c = (s & 7) ^ (r & 7);           // inverse-swizzled source chunk
        gload_lds16(gbase + (size_t)r * KK + c * 8, region + (size_t)s * 8);
    }
}

// stage a full 256x64 K-tile (A and W): 8 loads/thread
__device__ __forceinline__ void stage_tile(const f16* __restrict__ gA, const f16* __restrict__ gW,
                                           f16* As, f16* Bs, int tid) {
    stage_half(gA,                    As,        tid);
    stage_half(gA + (size_t)128 * KK, As + 8192, tid);
    stage_half(gW,                    Bs,        tid);
    stage_half(gW + (size_t)128 * KK, Bs + 8192, tid);
}

// swizzled fragment read from a [256][64] f16 tile
__device__ __forceinline__ f16x8 rd(const f16* base, int row, int chunk) {
    int c = chunk ^ (row & 7);
    return *(const f16x8*)(base + row * 64 + c * 8);
}

__device__ __forceinline__ void read12(const f16* Abase, const f16* Bbase,
                                       int arow, int brow, int kc,
                                       f16x8 a[8], f16x8 b[4]) {
#pragma unroll
    for (int m = 0; m < 8; ++m) a[m] = rd(Abase, arow + m * 16, kc);
#pragma unroll
    for (int n = 0; n < 4; ++n) b[n] = rd(Bbase, brow + n * 16, kc);
}

__device__ __forceinline__ float tanh_fast(float z) {
    float e = __expf(2.f * z);
    return 1.f - 2.f / (e + 1.f);
}

#define BAR() do { __builtin_amdgcn_sched_barrier(0); __builtin_amdgcn_s_barrier(); \
                   __builtin_amdgcn_sched_barrier(0); } while (0)

#define MFMA32(av, bv) do {                                                     \
    __builtin_amdgcn_s_setprio(1);                                              \
    _Pragma("unroll")                                                           \
    for (int m = 0; m < 8; ++m)                                                 \
        _Pragma("unroll")                                                       \
        for (int n = 0; n < 4; ++n)                                             \
            acc[m][n] = __builtin_amdgcn_mfma_f32_16x16x32_f16(av[m], bv[n],    \
                                                               acc[m][n], 0, 0, 0); \
    __builtin_amdgcn_s_setprio(0);                                              \
} while (0)

__global__ __launch_bounds__(512, 2) void gemm_tanh(const f16* __restrict__ A,
                                                    const f16* __restrict__ W,
                                                    const float* __restrict__ bias,
                                                    f16* __restrict__ C,
                                                    const float* __restrict__ hw,
                                                    float* __restrict__ pbuf) {
    __shared__ f16 As[2][BM * BK];   // 2 x 32 KiB
    __shared__ f16 Bs[2][BN * BK];   // 2 x 32 KiB

    const int tid  = threadIdx.x;
    const int lane = tid & 63;
    const int wid  = tid >> 6;        // 0..7
    const int wr   = wid >> 2;        // 0..1  (M half)
    const int wc   = wid & 3;         // 0..3  (N quarter)

    // T1: XCD-chunked bijective swizzle (nwg=1024, %8==0)
    const int cpx = gridDim.x >> 3;
    const int lin = ((int)blockIdx.x & 7) * cpx + ((int)blockIdx.x >> 3);
    const int tm  = (lin >> 2) * BM;
    const int tn  = (lin & 3) * BN;

    const f16* Ab = A + (size_t)tm * KK;
    const f16* Wb = W + (size_t)tn * KK;

    const int fr = lane & 15;         // fragment row within 16
    const int fc = lane >> 4;         // 16B k-chunk 0..3 within a 32-k step

    f32x4 acc[8][4];
#pragma unroll
    for (int i = 0; i < 8; ++i)
#pragma unroll
        for (int j = 0; j < 4; ++j)
            acc[i][j] = (f32x4){0.f, 0.f, 0.f, 0.f};

    // prologue: tile0 -> buf0, tile1 -> buf1 (16 loads/thread in flight)
    stage_tile(Ab,      Wb,      &As[0][0], &Bs[0][0], tid);
    stage_tile(Ab + 64, Wb + 64, &As[1][0], &Bs[1][0], tid);
    asm volatile("s_waitcnt vmcnt(8)" ::: "memory");   // tile0 landed
    BAR();

    const int arow = wr * 128 + fr;
    const int brow = wc * 64  + fr;

    for (int it = 0; it < NKTILE / 2; ++it) {
        const bool pf = (it + 1 < NKTILE / 2);
        f16x8 a0[8], b0[4], a1[8], b1[4];

        // ======== sub A: K-tile t=2it in buf0 ========
        read12(&As[0][0], &Bs[0][0], arow, brow, fc,     a0, b0);   // k0 group
        read12(&As[0][0], &Bs[0][0], arow, brow, 4 + fc, a1, b1);   // k1 group
        MFMA32(a0, b0);                                 // k1 reads drain under this
        asm volatile("s_waitcnt lgkmcnt(0)" ::: "memory");   // all buf0 reads retired
        BAR();
        if (pf) stage_tile(Ab + (size_t)(2 * it + 2) * BK, Wb + (size_t)(2 * it + 2) * BK,
                           &As[0][0], &Bs[0][0], tid);       // t+2 -> buf0
        MFMA32(a1, b1);                                 // gload issue overlaps
        if (pf) asm volatile("s_waitcnt vmcnt(8)" ::: "memory");   // tile t+1 landed
        else    asm volatile("s_waitcnt vmcnt(0)" ::: "memory");   // t=14: tile15 landed
        BAR();                                          // publish buf1

        // ======== sub B: K-tile t=2it+1 in buf1 ========
        read12(&As[1][0], &Bs[1][0], arow, brow, fc,     a0, b0);
        read12(&As[1][0], &Bs[1][0], arow, brow, 4 + fc, a1, b1);
        MFMA32(a0, b0);
        asm volatile("s_waitcnt lgkmcnt(0)" ::: "memory");   // all buf1 reads retired
        BAR();
        if (pf) stage_tile(Ab + (size_t)(2 * it + 3) * BK, Wb + (size_t)(2 * it + 3) * BK,
                           &As[1][0], &Bs[1][0], tid);       // t+2 -> buf1
        MFMA32(a1, b1);
        if (pf) asm volatile("s_waitcnt vmcnt(8)" ::: "memory");   // tile t+1 landed
        BAR();                                          // publish buf0
    }

    if (pbuf == nullptr) {
        // epilogue: bias + fast tanh, store f16 (mi outer: row-major store order)
#pragma unroll
        for (int mi = 0; mi < 8; ++mi) {
            const int r0 = tm + wr * 128 + mi * 16 + (fc << 2);
#pragma unroll
            for (int ni = 0; ni < 4; ++ni) {
                const int c = tn + wc * 64 + ni * 16 + fr;
                const float bv = bias[c];
#pragma unroll
                for (int q = 0; q < 4; ++q) {
                    float z = acc[mi][ni][q] + bv;
                    C[(size_t)(r0 + q) * NN + c] = (f16)tanh_fast(z);
                }
            }
        }
    } else {
        // fused-head epilogue: partial[row, nb] = sum over this block's 256
        // columns of tanh(acc + bias[c]) * hw[c].  All waves finished the
        // K-loop (loop ends with BAR), so As is reusable as a reduce buffer.
        float* red = (float*)&As[0][0];       // [256 rows][4 wc] floats = 4 KB
#pragma unroll
        for (int mi = 0; mi < 8; ++mi) {
            float s[4] = {0.f, 0.f, 0.f, 0.f};      // per q
#pragma unroll
            for (int ni = 0; ni < 4; ++ni) {
                const int c = tn + wc * 64 + ni * 16 + fr;
                const float bv = bias[c];
                const float wv = hw[c];
#pragma unroll
                for (int q = 0; q < 4; ++q)
                    s[q] += tanh_fast(acc[mi][ni][q] + bv) * wv;
            }
            // reduce across the 16 fr-lanes (same rows, different columns)
#pragma unroll
            for (int q = 0; q < 4; ++q) {
#pragma unroll
                for (int o = 1; o < 16; o <<= 1)
                    s[q] += __shfl_xor(s[q], o, 64);
            }
            if (fr == 0) {
                const int rloc = wr * 128 + mi * 16 + (fc << 2);
#pragma unroll
                for (int q = 0; q < 4; ++q)
                    red[(rloc + q) * 4 + wc] = s[q];
            }
        }
        __syncthreads();
        if (tid < 256) {
            const float4 v = *(const float4*)&red[tid * 4];
            pbuf[(size_t)(tm + tid) * 4 + (tn >> 8)] = v.x + v.y + v.z + v.w;
        }
    }
}

// ---------------- head final: out[m] = sum_nb partial[m][nb] + hb ----------------

__global__ void head_final(const float* __restrict__ pbuf, const float* __restrict__ hb,
                           float* __restrict__ out) {
    const int m = blockIdx.x * blockDim.x + threadIdx.x;
    const float4 v = *(const float4*)&pbuf[(size_t)m * 4];
    out[m] = v.x + v.y + v.z + v.w + hb[0];
}

// ---------------- launch ----------------

extern "C" void kernel_launch(void* const* d_in, const int* in_sizes, int n_in,
                              void* d_out, int out_size, void* d_ws, size_t ws_size,
                              hipStream_t stream) {
    const float* x    = (const float*)d_in[0];
    const float* Alog = (const float*)d_in[1];
    const float* Wls  = (const float*)d_in[2];
    const float* bls  = (const float*)d_in[3];
    const float* hw   = (const float*)d_in[4];
    const float* hb   = (const float*)d_in[5];
    float* out = (float*)d_out;

    char* ws = (char*)d_ws;
    const size_t hbytes = (size_t)MM * DD * sizeof(f16);   // 128 MiB
    f16* h0 = (f16*)ws;
    f16* h1 = (f16*)(ws + hbytes);
    char* scratch = ws + 2 * hbytes;
    float* carry = (float*)scratch;                         // 8 MiB, scan phase only
    f16*   wf    = (f16*)scratch;                           // 8 MiB, reused after scan
    float* pbuf  = (float*)h0;                              // 1 MiB, layer-4 partials
                                                            // (h0 free during layer 4)

    // 1. scan (chunked, 3 passes)
    scan_pass1<<<(NCHUNK * BD) / 256, 256, 0, stream>>>(x, Alog, h0, carry);
    scan_pass2<<<BD / 256, 256, 0, stream>>>(Alog, carry);
    scan_pass3<<<(NCHUNK * BD) / 256, 256, 0, stream>>>(Alog, carry, h0);

    // 2. weights fp32 -> fp16 (reuses carry region; stream-ordered after pass3)
    cvt_w<<<(NLAYERS * DD * DD / 4) / 256, 256, 0, stream>>>(Wls, wf, NLAYERS * DD * DD);

    // 3. four layers, ping-pong; layer 4 fuses the head dot-product
    dim3 grid((MM / BM) * (NN / BN)), blk(512);
    gemm_tanh<<<grid, blk, 0, stream>>>(h0, wf + 0 * (DD * DD), bls + 0 * DD, h1, nullptr, nullptr);
    gemm_tanh<<<grid, blk, 0, stream>>>(h1, wf + 1 * (DD * DD), bls + 1 * DD, h0, nullptr, nullptr);
    gemm_tanh<<<grid, blk, 0, stream>>>(h0, wf + 2 * (DD * DD), bls + 2 * DD, h1, nullptr, nullptr);
    gemm_tanh<<<grid, blk, 0, stream>>>(h1, wf + 3 * (DD * DD), bls + 3 * DD, nullptr, hw, pbuf);

    // 4. head: sum the 4 per-N-block partials + bias
    head_final<<<MM / 256, 256, 0, stream>>>(pbuf, hb, out);
}